// Round 11
// baseline (245.321 us; speedup 1.0000x reference)
//
#include <hip/hip_runtime.h>

#define DM 1024
#define NH 16
#define HD 64
#define BATCH 2
#define SEQ 2048
#define MROWS (BATCH*SEQ)   // 4096

typedef unsigned short u16;
typedef unsigned long long u64;
typedef __bf16 bf16x8 __attribute__((ext_vector_type(8)));
typedef float f32x4 __attribute__((ext_vector_type(4)));
typedef float f32x16 __attribute__((ext_vector_type(16)));
typedef unsigned int u32x4 __attribute__((ext_vector_type(4)));
typedef unsigned int __attribute__((address_space(1))) as1_uint;
typedef unsigned int __attribute__((address_space(3))) as3_uint;

__device__ __forceinline__ u16 f2bf(float f) {
  unsigned u = __builtin_bit_cast(unsigned, f);
  u += 0x7fffu + ((u >> 16) & 1u);
  return (u16)(u >> 16);
}
__device__ __forceinline__ float bf2f(u16 h) {
  return __builtin_bit_cast(float, ((unsigned)h) << 16);
}
__device__ __forceinline__ bf16x8 ld8(const u16* p) {
  return __builtin_bit_cast(bf16x8, *reinterpret_cast<const u32x4*>(p));
}
__device__ __forceinline__ void gl_lds16(const u16* g, void* lds) {
  __builtin_amdgcn_global_load_lds((const as1_uint*)(const void*)g,
                                   (as3_uint*)lds, 16, 0, 0);
}
// pack hi16(a)<<16 | hi16(b)  (bf16 truncation, 1 VALU op)
__device__ __forceinline__ unsigned pk2(float a, float b) {
  return __builtin_amdgcn_perm(__builtin_bit_cast(unsigned, a),
                               __builtin_bit_cast(unsigned, b), 0x07060302u);
}

// ---------- fused fp32 -> bf16 conversion (x + 5 weights, contiguous output) ----------
__global__ void convall_kernel(const float* __restrict__ x,
                               const float* __restrict__ w0, const float* __restrict__ w1,
                               const float* __restrict__ w2, const float* __restrict__ w3,
                               const float* __restrict__ w4, u16* __restrict__ out) {
  const size_t NX = (size_t)MROWS * DM;   // 4M
  size_t i = ((size_t)blockIdx.x * 256 + threadIdx.x) * 4;
  const float* src;
  size_t off;
  if (i < NX) { src = x; off = i; }
  else {
    size_t j = i - NX;
    int wsel = (int)(j >> 20);
    off = j & ((1u << 20) - 1);
    src = (wsel == 0) ? w0 : (wsel == 1) ? w1 : (wsel == 2) ? w2 : (wsel == 3) ? w3 : w4;
  }
  f32x4 v = *reinterpret_cast<const f32x4*>(src + off);
  out[i + 0] = f2bf(v[0]);
  out[i + 1] = f2bf(v[1]);
  out[i + 2] = f2bf(v[2]);
  out[i + 3] = f2bf(v[3]);
}

// ---------- RoPE cos/sin table ----------
__global__ void tab_kernel(float* __restrict__ tab) {
  int t = blockIdx.x * 256 + threadIdx.x;
  if (t >= SEQ * 32) return;
  int s = t >> 5, i = t & 31;
  float inv = powf(10000.0f, -(float)i / 32.0f);
  float f = (float)s * inv;
  tab[s * 64 + i] = cosf(f);
  tab[s * 64 + 32 + i] = sinf(f);
}

// ---------- QKV GEMM with fused RoPE (z<2) / transpose (z==2) epilogue ----------
// 128x64 tile, BK=32. Wave w owns rows w*32..w*32+31, all 64 cols (one head).
__global__ __launch_bounds__(256) void qkv_gemm(
    const u16* __restrict__ A, const u16* __restrict__ Bw,
    u16* __restrict__ Qr, u16* __restrict__ Kr, u16* __restrict__ Vt,
    const float* __restrict__ tab) {
  const int z = blockIdx.z;
  const u16* B = Bw + (size_t)z * DM * DM;
  int flat = blockIdx.y * 16 + blockIdx.x;       // nwg = 512
  flat = (flat & 7) * 64 + (flat >> 3);          // XCD-chunked, bijective
  const int bx = flat & 15, by = flat >> 4;
  const int m0 = by * 128;
  const int h = bx;                               // head == n-tile
  const int t = threadIdx.x, w = t >> 6, l = t & 63;
  const int lr = l & 15, lg = l >> 4;
  __shared__ __align__(16) u16 SM[8704];          // As[128*32] + Bs[64*32] | T[64][136]
  u16* As = SM;
  u16* Bs = SM + 4096;
  f32x4 acc[2][4] = {};
  const int srow = t >> 2, sc8 = (t & 3) * 8;
  const u16* gA = A + (size_t)(m0 + srow) * DM + sc8;
  const u16* gB = B + (size_t)(h * 64 + srow) * DM + sc8;
  char* lA = (char*)As + w * 1024;
  char* lB = (char*)Bs + w * 1024;
  const size_t rstep = (size_t)64 * DM;

  for (int kt = 0; kt < DM; kt += 32) {
    gl_lds16(gA + kt, lA);
    gl_lds16(gA + kt + rstep, lA + 4096);
    gl_lds16(gB + kt, lB);
    __syncthreads();
    bf16x8 af[2], bfr[4];
    af[0] = ld8(&As[(w * 32 + lr) * 32 + lg * 8]);
    af[1] = ld8(&As[(w * 32 + 16 + lr) * 32 + lg * 8]);
#pragma unroll
    for (int ni = 0; ni < 4; ++ni) bfr[ni] = ld8(&Bs[(ni * 16 + lr) * 32 + lg * 8]);
#pragma unroll
    for (int mi = 0; mi < 2; ++mi)
#pragma unroll
      for (int ni = 0; ni < 4; ++ni)
        acc[mi][ni] = __builtin_amdgcn_mfma_f32_16x16x32_bf16(af[mi], bfr[ni], acc[mi][ni], 0, 0, 0);
    __syncthreads();
  }

  if (z < 2) {
    u16* Out = (z == 0) ? Qr : Kr;
#pragma unroll
    for (int mi = 0; mi < 2; ++mi)
#pragma unroll
      for (int r = 0; r < 4; ++r) {
        const int row = m0 + w * 32 + mi * 16 + lg * 4 + r;
        const int b = row >> 11, s = row & (SEQ - 1);
        const size_t ob = ((size_t)(b * NH + h) * SEQ + s) * 64;
#pragma unroll
        for (int ni = 0; ni < 2; ++ni) {
          const int i = ni * 16 + lr;
          const float c = tab[s * 64 + i], sn = tab[s * 64 + 32 + i];
          const float v1 = acc[mi][ni][r], v2 = acc[mi][ni + 2][r];
          Out[ob + i] = f2bf(v1 * c - v2 * sn);
          Out[ob + 32 + i] = f2bf(v2 * c + v1 * sn);
        }
      }
  } else {
    // V: transpose 128x64 tile -> Vt[bh][d][s] via LDS T[64][136]
    u16* T = SM;
#pragma unroll
    for (int mi = 0; mi < 2; ++mi)
#pragma unroll
      for (int ni = 0; ni < 4; ++ni) {
        const int cc = ni * 16 + lr;
        const int rw = w * 32 + mi * 16 + lg * 4;
#pragma unroll
        for (int r = 0; r < 4; ++r) T[cc * 136 + rw + r] = f2bf(acc[mi][ni][r]);
      }
    __syncthreads();
    const int d = t >> 2, seg = t & 3;
    const int b = m0 >> 11, sbase = (m0 & (SEQ - 1)) + seg * 32;
    u16* dst = Vt + ((size_t)(b * NH + h) * 64 + d) * SEQ + sbase;
    const u16* srcT = T + d * 136 + seg * 32;
#pragma unroll
    for (int j = 0; j < 4; ++j)
      *reinterpret_cast<u32x4*>(dst + j * 8) =
          *reinterpret_cast<const u32x4*>(srcT + j * 8);
  }
}

// ---------- Wo / Wg GEMM: 128x64 tile, BK=32, XCD-swizzled ----------
// MODE 1: store bf16 only.  MODE 2: Cf = bf2f(mult)*sigmoid(acc+bias)
template <int MODE>
__global__ __launch_bounds__(256) void gemm_bt(
    const u16* __restrict__ A, const u16* __restrict__ B,
    u16* __restrict__ Cb, float* __restrict__ Cf,
    const float* __restrict__ bias, const u16* __restrict__ mult,
    int M, int N, int K) {
  const int gx = gridDim.x;
  int nwg = gx * gridDim.y;
  int flat = blockIdx.y * gx + blockIdx.x;
  flat = (flat & 7) * (nwg >> 3) + (flat >> 3);
  const int bx = flat % gx, by = flat / gx;
  A += (size_t)by * 128 * K;
  B += (size_t)bx * 64 * K;
  if constexpr (MODE == 1) Cb += (size_t)by * 128 * N + bx * 64;
  if constexpr (MODE == 2) {
    Cf += (size_t)by * 128 * N + bx * 64;
    bias += bx * 64;
    mult += (size_t)by * 128 * N + bx * 64;
  }
  const int t = threadIdx.x, w = t >> 6;
  const int l = t & 63;
  const int wr = w >> 1, wc = w & 1;
  const int lr = l & 15, lg = l >> 4;
  __shared__ __align__(16) u16 As[128 * 32];
  __shared__ __align__(16) u16 Bs[64 * 32];
  f32x4 acc[4][2] = {};
  const int srow = t >> 2;
  const int sc8 = (t & 3) * 8;
  const u16* gA = A + (size_t)srow * K + sc8;
  const u16* gB = B + (size_t)srow * K + sc8;
  char* lA = (char*)As + w * 1024;
  char* lB = (char*)Bs + w * 1024;
  const size_t rstep = (size_t)64 * K;

  for (int kt = 0; kt < K; kt += 32) {
    gl_lds16(gA + kt, lA);
    gl_lds16(gA + kt + rstep, lA + 4096);
    gl_lds16(gB + kt, lB);
    __syncthreads();
    bf16x8 af[4], bfr[2];
#pragma unroll
    for (int i = 0; i < 4; ++i)
      af[i] = ld8(&As[(wr * 64 + i * 16 + lr) * 32 + lg * 8]);
#pragma unroll
    for (int i = 0; i < 2; ++i)
      bfr[i] = ld8(&Bs[(wc * 32 + i * 16 + lr) * 32 + lg * 8]);
#pragma unroll
    for (int mi = 0; mi < 4; ++mi)
#pragma unroll
      for (int ni = 0; ni < 2; ++ni)
        acc[mi][ni] = __builtin_amdgcn_mfma_f32_16x16x32_bf16(af[mi], bfr[ni], acc[mi][ni], 0, 0, 0);
    __syncthreads();
  }
#pragma unroll
  for (int mi = 0; mi < 4; ++mi)
#pragma unroll
    for (int ni = 0; ni < 2; ++ni)
#pragma unroll
      for (int r = 0; r < 4; ++r) {
        int row = wr * 64 + mi * 16 + lg * 4 + r;
        int col = wc * 32 + ni * 16 + lr;
        size_t idx = (size_t)row * N + col;
        float v = acc[mi][ni][r];
        if constexpr (MODE == 1) {
          Cb[idx] = f2bf(v);
        } else {
          float g = 1.0f / (1.0f + __expf(-(v + bias[col])));
          Cf[idx] = bf2f(mult[idx]) * g;
        }
      }
}

// ---------- flash attention: 1 wave/block, 32 q-rows, 32x32 MFMA, no LDS, no barriers ----------
// Swapped QK^T (lane owns q = l&31); PV B-frag built via one lane<->lane^32 exchange.
// K,V direct from global (L2-resident: 4 heads/XCD). Fixed-M softmax, deferred l-reduce.
__global__ __launch_bounds__(64) void attn_kernel(
    const u16* __restrict__ Q, const u16* __restrict__ K, const u16* __restrict__ Vt,
    u16* __restrict__ O) {
  const int f = blockIdx.x;                 // 0..2047
  const int i = f >> 3;                     // 0..255
  const int bh = (f & 7) * 4 + (i & 3);     // 4 heads per XCD
  const int j = i >> 2;                     // 0..63
  const int u = j & 31;
  const int strip = (j >> 5) ? u : 63 - u;  // paired (u, 63-u) -> balanced per CU
  const int qw0 = strip * 32;
  const int nt = (strip >> 1) + 1;

  const int l = threadIdx.x;
  const int r31 = l & 31, hi = l >> 5;
  const size_t base = (size_t)bh * SEQ * 64;
  const size_t vbase = (size_t)bh * 64 * SEQ;

  // Q fragments (B-operand): lane holds Q[qw0+r31][s*16+hi*8 .. +8)
  bf16x8 qf[4];
  const u16* qp = Q + base + (size_t)(qw0 + r31) * 64 + hi * 8;
#pragma unroll
  for (int s = 0; s < 4; ++s) qf[s] = ld8(qp + s * 16);

  f32x16 oacc[2] = {};
  float l_part = 0.0f;

  const u16* Kp = K + base + (size_t)r31 * 64 + hi * 8;
  const u16* Vp = Vt + vbase + (size_t)r31 * SEQ + hi * 8;

#define LOADK(dst, tile) do { const size_t kvo_ = (size_t)(tile) * 4096;        \
    _Pragma("unroll") for (int s_ = 0; s_ < 4; ++s_) {                          \
      dst[0][s_] = ld8(Kp + kvo_ + s_ * 16);                                    \
      dst[1][s_] = ld8(Kp + kvo_ + 2048 + s_ * 16); } } while (0)

  bf16x8 kf[2][4], kn[2][4];
  LOADK(kf, 0);

  for (int tk = 0; tk < nt; ++tk) {
    const int kv0 = tk * 64;
    // V fragments (A-operand for PV), issued early: vf[kvh][ksl][dm]
    bf16x8 vf[2][2][2];
#pragma unroll
    for (int kvh = 0; kvh < 2; ++kvh)
#pragma unroll
      for (int ksl = 0; ksl < 2; ++ksl)
#pragma unroll
        for (int dm = 0; dm < 2; ++dm)
          vf[kvh][ksl][dm] =
              ld8(Vp + (size_t)dm * 32 * SEQ + kv0 + kvh * 32 + ksl * 16);
    if (tk + 1 < nt) LOADK(kn, tk + 1);

    // QK^T: st[kvh] = S^T[kv 32][q 32]
    f32x16 st[2];
#pragma unroll
    for (int kvh = 0; kvh < 2; ++kvh) {
      f32x16 z{};
#pragma unroll
      for (int s = 0; s < 4; ++s)
        z = __builtin_amdgcn_mfma_f32_32x32x16_bf16(kf[kvh][s], qf[s], z, 0, 0, 0);
      st[kvh] = z;
    }
    // fixed-M softmax: p = exp2(st*c - 12)
    float p[2][16];
#pragma unroll
    for (int kvh = 0; kvh < 2; ++kvh)
#pragma unroll
      for (int r = 0; r < 16; ++r)
        p[kvh][r] = fmaf(st[kvh][r], 0.1803368801f, -12.0f);
    if (tk == nt - 1) {
#pragma unroll
      for (int kvh = 0; kvh < 2; ++kvh)
#pragma unroll
        for (int r = 0; r < 16; ++r) {
          const int kv_abs = kv0 + kvh * 32 + (r & 3) + 4 * hi + 8 * (r >> 2);
          if (kv_abs > qw0 + r31) p[kvh][r] = -1e30f;
        }
    }
    float acc_l = 0.0f;
#pragma unroll
    for (int kvh = 0; kvh < 2; ++kvh) {
#pragma unroll
      for (int r = 0; r < 16; ++r) p[kvh][r] = exp2f(p[kvh][r]);
      float a = (p[kvh][0] + p[kvh][1]) + (p[kvh][2] + p[kvh][3]);
      float b2 = (p[kvh][4] + p[kvh][5]) + (p[kvh][6] + p[kvh][7]);
      float c2 = (p[kvh][8] + p[kvh][9]) + (p[kvh][10] + p[kvh][11]);
      float d2 = (p[kvh][12] + p[kvh][13]) + (p[kvh][14] + p[kvh][15]);
      acc_l += (a + b2) + (c2 + d2);
    }
    l_part += acc_l;
    // pack P -> bf16 dwords; build PV B-frags via lane^32 exchange; PV MFMA
#pragma unroll
    for (int kvh = 0; kvh < 2; ++kvh) {
      unsigned dw[8];
#pragma unroll
      for (int m = 0; m < 8; ++m) dw[m] = pk2(p[kvh][2 * m + 1], p[kvh][2 * m]);
#pragma unroll
      for (int ksl = 0; ksl < 2; ++ksl) {
        const unsigned v0 = hi ? dw[4 * ksl + 0] : dw[4 * ksl + 2];
        const unsigned v1 = hi ? dw[4 * ksl + 1] : dw[4 * ksl + 3];
        const unsigned s0 = (unsigned)__shfl((int)v0, l ^ 32);
        const unsigned s1 = (unsigned)__shfl((int)v1, l ^ 32);
        u32x4 pw;
        pw[0] = hi ? s0 : dw[4 * ksl + 0];
        pw[1] = hi ? s1 : dw[4 * ksl + 1];
        pw[2] = hi ? dw[4 * ksl + 2] : s0;
        pw[3] = hi ? dw[4 * ksl + 3] : s1;
        const bf16x8 pfrag = __builtin_bit_cast(bf16x8, pw);
#pragma unroll
        for (int dm = 0; dm < 2; ++dm)
          oacc[dm] = __builtin_amdgcn_mfma_f32_32x32x16_bf16(
              vf[kvh][ksl][dm], pfrag, oacc[dm], 0, 0, 0);
      }
    }
    // rotate prefetch
#pragma unroll
    for (int kvh = 0; kvh < 2; ++kvh)
#pragma unroll
      for (int s = 0; s < 4; ++s) kf[kvh][s] = kn[kvh][s];
  }
#undef LOADK
  // epilogue: l-reduce (single xor-32), normalize, packed store
  const float ls = l_part + __shfl_xor(l_part, 32);
  const float inv = 1.0f / ls;
  const int q_abs = qw0 + r31;
  const int b = bh >> 4, hh = bh & 15;
  u16* Orow = O + ((size_t)(b * SEQ + q_abs)) * DM + hh * 64;
#pragma unroll
  for (int dm = 0; dm < 2; ++dm)
#pragma unroll
    for (int rr = 0; rr < 4; ++rr) {
      const float a0 = oacc[dm][4 * rr + 0] * inv;
      const float a1 = oacc[dm][4 * rr + 1] * inv;
      const float a2 = oacc[dm][4 * rr + 2] * inv;
      const float a3 = oacc[dm][4 * rr + 3] * inv;
      const u64 wv = (u64)pk2(a1, a0) | ((u64)pk2(a3, a2) << 32);
      *reinterpret_cast<u64*>(Orow + dm * 32 + 8 * rr + 4 * hi) = wv;
    }
}

extern "C" void kernel_launch(void* const* d_in, const int* in_sizes, int n_in,
                              void* d_out, int out_size, void* d_ws, size_t ws_size,
                              hipStream_t stream) {
  const float* x = (const float*)d_in[0];
  const float* Wq = (const float*)d_in[1];
  const float* Wk = (const float*)d_in[2];
  const float* Wv = (const float*)d_in[3];
  const float* Wo = (const float*)d_in[4];
  const float* Wg = (const float*)d_in[5];
  const float* bg = (const float*)d_in[6];
  float* out = (float*)d_out;

  const size_t NX = (size_t)MROWS * DM;  // 4M
  const size_t NW = (size_t)DM * DM;     // 1M
  u16* xbf = (u16*)d_ws;
  u16* wbf = xbf + NX;            // 5 weights (Wq,Wk,Wv,Wo,Wg)
  u16* qkvr = wbf + 5 * NW;       // Qr, Kr [BH][S][64]; Vt [BH][64][S]
  u16* attn = qkvr + 3 * NX;      // [B][S][DM]
  u16* outbf = attn + NX;         // [B][S][DM]
  float* tab = (float*)(outbf + NX);

  // 1. fp32 -> bf16 (x + 5 weights)
  convall_kernel<<<(NX + 5 * NW) / 1024, 256, 0, stream>>>(x, Wq, Wk, Wv, Wo, Wg, xbf);
  // 2. rope table
  tab_kernel<<<(SEQ * 32) / 256, 256, 0, stream>>>(tab);
  // 3. QKV projections + fused RoPE / V-transpose
  qkv_gemm<<<dim3(16, 32, 3), 256, 0, stream>>>(
      xbf, wbf, qkvr, qkvr + NX, qkvr + 2 * NX, tab);
  // 4. attention
  attn_kernel<<<dim3(2048), 64, 0, stream>>>(
      qkvr, qkvr + NX, qkvr + 2 * NX, attn);
  // 5. output projection (bf16 only)
  gemm_bt<1><<<dim3(16, 32), 256, 0, stream>>>(
      attn, wbf + 3 * NW, outbf, nullptr, nullptr, nullptr, MROWS, DM, DM);
  // 6. gate + final (fp32 out)
  gemm_bt<2><<<dim3(16, 32), 256, 0, stream>>>(
      outbf, wbf + 4 * NW, nullptr, out, bg, outbf, MROWS, DM, DM);
}